// Round 1
// baseline (343.199 us; speedup 1.0000x reference)
//
#include <hip/hip_runtime.h>

// Depthwise transposed conv K=3, S=2, SAME. x:(8,128,128,128) NHWC fp32,
// w:(3,3,1,128) HWIO fp32 -> out:(8,256,256,128) fp32.
//
// out[2y+dy, 2x+dx, c] expressed per 2x2 tile from inputs {y,y-1}x{x,x-1}.
// One thread = one (n,y,x,c4) with c4 a float4 chunk of the 128 channels.

__device__ __forceinline__ float4 f4_fma(float4 a, float4 b, float4 c) {
    return make_float4(fmaf(a.x, b.x, c.x), fmaf(a.y, b.y, c.y),
                       fmaf(a.z, b.z, c.z), fmaf(a.w, b.w, c.w));
}
__device__ __forceinline__ float4 f4_mul(float4 a, float4 b) {
    return make_float4(a.x * b.x, a.y * b.y, a.z * b.z, a.w * b.w);
}

__global__ __launch_bounds__(256) void upsample_tconv_kernel(
    const float* __restrict__ x, const float* __restrict__ w,
    float* __restrict__ out)
{
    // 8 * 128 * 128 * 32 = 4,194,304 threads total
    int idx = blockIdx.x * blockDim.x + threadIdx.x;
    int c4 = idx & 31;            // float4 index within 128 channels
    int xi = (idx >> 5) & 127;    // input column
    int yi = (idx >> 12) & 127;   // input row
    int n  = idx >> 19;           // batch

    const float4* wv = (const float4*)w;  // w[j][i][c] -> (j*3+i)*32 + c4
    float4 w00 = wv[0 * 32 + c4];
    float4 w01 = wv[1 * 32 + c4];
    float4 w02 = wv[2 * 32 + c4];
    float4 w10 = wv[3 * 32 + c4];
    float4 w11 = wv[4 * 32 + c4];
    float4 w12 = wv[5 * 32 + c4];
    float4 w20 = wv[6 * 32 + c4];
    float4 w21 = wv[7 * 32 + c4];
    float4 w22 = wv[8 * 32 + c4];

    const float4* xv = (const float4*)x;  // ((n*128+y)*128+x)*32 + c4
    int base = ((n * 128 + yi) * 128 + xi) * 32 + c4;
    const float4 zero = make_float4(0.f, 0.f, 0.f, 0.f);
    float4 x00 = xv[base];                                     // x[y,   x  ]
    float4 x0m = (xi > 0) ? xv[base - 32] : zero;              // x[y,   x-1]
    float4 xm0 = (yi > 0) ? xv[base - 128 * 32] : zero;        // x[y-1, x  ]
    float4 xmm = (yi > 0 && xi > 0) ? xv[base - 128 * 32 - 32] : zero;

    // out[oy,ox]: ((n*256+oy)*256+ox)*32 + c4
    int oy = yi << 1, ox = xi << 1;
    int obase = ((n * 256 + oy) * 256 + ox) * 32 + c4;
    float4* ov = (float4*)out;

    float4 o00 = f4_mul(w00, x00);
    o00 = f4_fma(w02, x0m, o00);
    o00 = f4_fma(w20, xm0, o00);
    o00 = f4_fma(w22, xmm, o00);
    ov[obase] = o00;

    float4 o01 = f4_mul(w01, x00);
    o01 = f4_fma(w21, xm0, o01);
    ov[obase + 32] = o01;

    float4 o10 = f4_mul(w10, x00);
    o10 = f4_fma(w12, x0m, o10);
    ov[obase + 256 * 32] = o10;

    float4 o11 = f4_mul(w11, x00);
    ov[obase + 256 * 32 + 32] = o11;
}

extern "C" void kernel_launch(void* const* d_in, const int* in_sizes, int n_in,
                              void* d_out, int out_size, void* d_ws, size_t ws_size,
                              hipStream_t stream) {
    const float* x = (const float*)d_in[0];
    const float* w = (const float*)d_in[1];
    float* out = (float*)d_out;

    // 8*128*128*32 threads / 256 per block = 16384 blocks
    upsample_tconv_kernel<<<dim3(16384), dim3(256), 0, stream>>>(x, w, out);
}

// Round 3
// 328.054 us; speedup vs baseline: 1.0462x; 1.0462x over previous
//
#include <hip/hip_runtime.h>

// Depthwise transposed conv K=3, S=2, SAME. x:(8,128,128,128) NHWC fp32,
// w:(3,3,1,128) HWIO fp32 -> out:(8,256,256,128) fp32.
//
// Thread = (n, y, ox, c4): produces out[2y, ox] and out[2y+1, ox] (one float4
// of channels each). Lane bit 5 carries ox parity so each 64-lane store is a
// single contiguous 1 KiB segment. Output is streamed with nontemporal
// stores (write-once, never re-read) to keep L2 free for x-row reuse.
//
// out[2y+0, 2t+px] = w[0][px]*x[y,t] + [px==0]*w[0][2]*x[y,t-1]
//                  + w[2][px]*x[y-1,t] + [px==0]*w[2][2]*x[y-1,t-1]
// out[2y+1, 2t+px] = w[1][px]*x[y,t] + [px==0]*w[1][2]*x[y,t-1]

typedef float v4f __attribute__((ext_vector_type(4)));

__global__ __launch_bounds__(256) void upsample_tconv_kernel(
    const float* __restrict__ x, const float* __restrict__ w,
    float* __restrict__ out)
{
    // 8 * 128 * 256 * 32 = 8,388,608 threads
    int idx = blockIdx.x * blockDim.x + threadIdx.x;
    int c4 = idx & 31;            // float4 chunk of 128 channels
    int ox = (idx >> 5) & 255;    // output column (parity = lane bit 5)
    int y  = (idx >> 13) & 127;   // input row
    int n  = idx >> 20;           // batch

    int px = ox & 1;              // output-column parity
    int xq = ox >> 1;             // input column

    const v4f* wv = (const v4f*)w;  // w[j][i][c] -> (j*3+i)*32 + c4
    const v4f zero = (v4f)(0.f);

    v4f wa0 = wv[(0 * 3 + px) * 32 + c4];   // w[0][px]
    v4f wa1 = wv[(1 * 3 + px) * 32 + c4];   // w[1][px]
    v4f wc0 = wv[(2 * 3 + px) * 32 + c4];   // w[2][px]
    v4f wb0 = wv[(0 * 3 + 2) * 32 + c4];    // w[0][2]
    v4f wb1 = wv[(1 * 3 + 2) * 32 + c4];    // w[1][2]
    v4f wd0 = wv[(2 * 3 + 2) * 32 + c4];    // w[2][2]
    if (px) { wb0 = zero; wb1 = zero; wd0 = zero; }  // odd column: no i=2 taps

    const v4f* xv = (const v4f*)x;  // ((n*128+y)*128+xq)*32 + c4
    int base = ((n * 128 + y) * 128 + xq) * 32 + c4;
    v4f xa = xv[base];                                    // x[y,   t  ]
    v4f xb = (xq > 0) ? xv[base - 32] : zero;             // x[y,   t-1]
    v4f xc = (y > 0) ? xv[base - 128 * 32] : zero;        // x[y-1, t  ]
    v4f xd = (y > 0 && xq > 0) ? xv[base - 128 * 32 - 32] : zero;

    v4f o0 = wa0 * xa + wb0 * xb + wc0 * xc + wd0 * xd;   // out[2y,   ox]
    v4f o1 = wa1 * xa + wb1 * xb;                         // out[2y+1, ox]

    int oy = y << 1;
    v4f* ov = (v4f*)out;
    int ob = ((n * 256 + oy) * 256 + ox) * 32 + c4;
    __builtin_nontemporal_store(o0, &ov[ob]);
    __builtin_nontemporal_store(o1, &ov[ob + 256 * 32]);
}

extern "C" void kernel_launch(void* const* d_in, const int* in_sizes, int n_in,
                              void* d_out, int out_size, void* d_ws, size_t ws_size,
                              hipStream_t stream) {
    const float* x = (const float*)d_in[0];
    const float* w = (const float*)d_in[1];
    float* out = (float*)d_out;

    // 8,388,608 threads / 256 = 32768 blocks
    upsample_tconv_kernel<<<dim3(32768), dim3(256), 0, stream>>>(x, w, out);
}